// Round 4
// baseline (5170.280 us; speedup 1.0000x reference)
//
#include <hip/hip_runtime.h>

// Farthest Point Sampling: B=16 batches, N=65536 points, S=2048 samples.
// Output: gathered coords (B, S, 3) fp32.
//
// Round-4: round-3 structure (16 blocks/batch x 256 thr, 16 register-resident
// points/thread, DPP reductions, 1 polling wave, seq-tagged parity slots)
// with the serial chain shortened:
//  1. Winner COORDS travel through the slots (32B: 4 seq-tagged u64 words)
//     -- kills the dependent ~500cy L3 coord fetch. Coords are carried
//     through the per-thread argmax (cndmask), never dynamically indexed.
//  2. NO __syncthreads in the loop: intra-block handoffs are seq-tagged LDS
//     release/acquire spins (wave->publisher, winner->all-waves).
//  3. Pipelined global poll (one 4-load set in flight ahead of the checked
//     set) -- cuts detect from ~1.5 to ~1.0 L3 round trips.
// Safety: every buffer's writer for iteration k+1 must first pass the
// broadcast of k, which requires every consumer of k to have finished
// (applies to LDS slots and to parity-global ABA alike). Seq tags 1..2048
// never match the 0xAAAA ws poison; LDS tags are zeroed once before the loop.
//
// Arithmetic matches numpy bit-exactly: no FMA (__f*_rn), sum order
// ((dx*dx+dy*dy)+dz*dz), fminf, first-occurrence argmax via inverted-index
// (validated rounds 1/3: absmax 0.0).

#define BATCHES 16
#define NPTS    65536
#define NSAMP   2048
#define PB      16                    // blocks per batch
#define TPB     256                   // threads per block
#define WPB     (TPB / 64)            // 4 waves per block
#define PPT     (NPTS / (PB * TPB))   // 16 points per thread

// DPP ctrl: 0xB1 quad_perm xor1, 0x4E quad_perm xor2, 0x141 row_half_mirror,
// 0x140 row_mirror, 0x142 row_bcast15, 0x143 row_bcast31.

template <int CTRL>
__device__ __forceinline__ float dppmax_f(float x) {
  int y = __builtin_amdgcn_update_dpp(0, __float_as_int(x), CTRL, 0xF, 0xF, true);
  float yf = __int_as_float(y);
  return x > yf ? x : yf;  // distances >= 0 so bound_ctrl 0-fill is identity
}

template <int CTRL>
__device__ __forceinline__ unsigned dppmax_u(unsigned x) {
  unsigned y = (unsigned)__builtin_amdgcn_update_dpp(0, (int)x, CTRL, 0xF, 0xF, true);
  return x > y ? x : y;
}

template <int CTRL>
__device__ __forceinline__ unsigned long long dppmax_u64(unsigned long long x) {
  unsigned lo = (unsigned)x, hi = (unsigned)(x >> 32);
  unsigned plo = (unsigned)__builtin_amdgcn_update_dpp(0, (int)lo, CTRL, 0xF, 0xF, true);
  unsigned phi = (unsigned)__builtin_amdgcn_update_dpp(0, (int)hi, CTRL, 0xF, 0xF, true);
  unsigned long long p = ((unsigned long long)phi << 32) | plo;
  return p > x ? p : x;
}

__global__ __launch_bounds__(TPB) void fps_kernel(
    const float* __restrict__ coords,
    float* __restrict__ out,
    unsigned long long* __restrict__ slots) {
  const int blk  = blockIdx.x;
  const int b    = blk >> 4;    // batch
  const int r    = blk & 15;    // rank within batch
  const int t    = threadIdx.x;
  const int lane = t & 63;
  const int wave = t >> 6;

  const float* __restrict__ cb = coords + (size_t)b * NPTS * 3;
  const int base = r * (TPB * PPT);

  // Register-resident points and closest-distance array.
  float px[PPT], py[PPT], pz[PPT], cl[PPT];
#pragma unroll
  for (int k = 0; k < PPT; ++k) {
    int idx = base + k * TPB + t;
    px[k] = cb[3 * idx + 0];
    py[k] = cb[3 * idx + 1];
    pz[k] = cb[3 * idx + 2];
    cl[k] = __builtin_inff();
  }

  __shared__ unsigned long long s_wkey[WPB];      // val32|invidx16|seq16
  __shared__ float s_wx[WPB], s_wy[WPB], s_wz[WPB];
  __shared__ unsigned long long s_bxy;            // xbits32|ybits32
  __shared__ unsigned long long s_bz;             // zbits32|pad16|seq16

  if (t < WPB) s_wkey[t] = 0;
  if (t == 0) s_bz = 0;
  __syncthreads();  // one-time LDS tag init

  // Initial selected point: index 0 (matches reference).
  float sx = cb[0], sy = cb[1], sz = cb[2];

  for (int it = 0; it < NSAMP; ++it) {
    const unsigned long long seq = (unsigned long long)(it + 1);

    // --- distance update + per-thread argmax, carrying winner coords
    // (ascending idx => '>' keeps first occurrence within thread) ---
    float bestv = -1.0f, bx = 0.0f, by = 0.0f, bz = 0.0f;
    int bestidx = 0;
#pragma unroll
    for (int k = 0; k < PPT; ++k) {
      float dx = __fsub_rn(sx, px[k]);
      float dy = __fsub_rn(sy, py[k]);
      float dz = __fsub_rn(sz, pz[k]);
      float d  = __fadd_rn(__fadd_rn(__fmul_rn(dx, dx), __fmul_rn(dy, dy)),
                           __fmul_rn(dz, dz));
      float c  = fminf(cl[k], d);
      cl[k] = c;
      if (c > bestv) {
        bestv = c; bestidx = base + k * TPB + t;
        bx = px[k]; by = py[k]; bz = pz[k];
      }
    }

    // --- intra-wave value max via DPP ---
    float v = bestv;
    v = dppmax_f<0xB1>(v);
    v = dppmax_f<0x4E>(v);
    v = dppmax_f<0x141>(v);
    v = dppmax_f<0x140>(v);
    v = dppmax_f<0x142>(v);
    v = dppmax_f<0x143>(v);
    v = __int_as_float(__builtin_amdgcn_readlane(__float_as_int(v), 63));

    // --- first-occurrence index among value-tied lanes ---
    unsigned inv = (bestv == v) ? (unsigned)(0x20000 - bestidx) : 0u;
    inv = dppmax_u<0xB1>(inv);
    inv = dppmax_u<0x4E>(inv);
    inv = dppmax_u<0x141>(inv);
    inv = dppmax_u<0x140>(inv);
    inv = dppmax_u<0x142>(inv);
    inv = dppmax_u<0x143>(inv);
    int widx = 0x20000 - (int)(unsigned)__builtin_amdgcn_readlane((int)inv, 63);

    // --- wave winner hands key + coords to LDS (release on key) ---
    if (bestv == v && bestidx == widx) {  // unique lane
      s_wx[wave] = bx; s_wy[wave] = by; s_wz[wave] = bz;
      unsigned long long wk =
          ((unsigned long long)__float_as_uint(v) << 32) |
          ((unsigned long long)(unsigned)(65535 - widx) << 16) | seq;
      __hip_atomic_store(&s_wkey[wave], wk, __ATOMIC_RELEASE,
                         __HIP_MEMORY_SCOPE_WORKGROUP);
    }

    unsigned long long* bs =
        slots + ((size_t)(((it + 1) & 1) * BATCHES + b)) * (PB * 4);

    if (wave == 0) {
      // --- lanes 0-3: collect wave results, reduce, winner publishes ---
      if (lane < WPB) {
        unsigned long long wk;
        do {
          wk = __hip_atomic_load(&s_wkey[lane], __ATOMIC_ACQUIRE,
                                 __HIP_MEMORY_SCOPE_WORKGROUP);
        } while ((wk & 0xFFFFull) != seq);
        float cx = s_wx[lane], cy = s_wy[lane], cz = s_wz[lane];
        unsigned long long m = wk;
        m = dppmax_u64<0xB1>(m);
        m = dppmax_u64<0x4E>(m);
        if (wk == m) {  // unique winner (distinct invidx)
          unsigned long long* sp = bs + r * 4;
          __hip_atomic_store(sp + 0, wk, __ATOMIC_RELAXED,
                             __HIP_MEMORY_SCOPE_AGENT);
          __hip_atomic_store(sp + 1,
              ((unsigned long long)__float_as_uint(cx) << 32) | seq,
              __ATOMIC_RELAXED, __HIP_MEMORY_SCOPE_AGENT);
          __hip_atomic_store(sp + 2,
              ((unsigned long long)__float_as_uint(cy) << 32) | seq,
              __ATOMIC_RELAXED, __HIP_MEMORY_SCOPE_AGENT);
          __hip_atomic_store(sp + 3,
              ((unsigned long long)__float_as_uint(cz) << 32) | seq,
              __ATOMIC_RELAXED, __HIP_MEMORY_SCOPE_AGENT);
        }
      }
      // --- lanes 0-15: pipelined poll of the 16 peer slots ---
      if (lane < PB) {
        const unsigned long long* ps = bs + lane * 4;
        unsigned long long a0, a1, a2, a3;
        a0 = __hip_atomic_load(ps + 0, __ATOMIC_RELAXED, __HIP_MEMORY_SCOPE_AGENT);
        a1 = __hip_atomic_load(ps + 1, __ATOMIC_RELAXED, __HIP_MEMORY_SCOPE_AGENT);
        a2 = __hip_atomic_load(ps + 2, __ATOMIC_RELAXED, __HIP_MEMORY_SCOPE_AGENT);
        a3 = __hip_atomic_load(ps + 3, __ATOMIC_RELAXED, __HIP_MEMORY_SCOPE_AGENT);
        while (true) {
          unsigned long long b0, b1, b2, b3;
          b0 = __hip_atomic_load(ps + 0, __ATOMIC_RELAXED, __HIP_MEMORY_SCOPE_AGENT);
          b1 = __hip_atomic_load(ps + 1, __ATOMIC_RELAXED, __HIP_MEMORY_SCOPE_AGENT);
          b2 = __hip_atomic_load(ps + 2, __ATOMIC_RELAXED, __HIP_MEMORY_SCOPE_AGENT);
          b3 = __hip_atomic_load(ps + 3, __ATOMIC_RELAXED, __HIP_MEMORY_SCOPE_AGENT);
          if ((((a0 ^ seq) | (a1 ^ seq) | (a2 ^ seq) | (a3 ^ seq)) & 0xFFFFull)
              == 0ull)
            break;
          a0 = b0; a1 = b1; a2 = b2; a3 = b3;
        }
        unsigned long long pk = a0;
        float gx = __uint_as_float((unsigned)(a1 >> 32));
        float gy = __uint_as_float((unsigned)(a2 >> 32));
        float gz = __uint_as_float((unsigned)(a3 >> 32));

        // 16-lane u64 max (seq bits equal -> tie-free full-word compare).
        unsigned long long m = pk;
        m = dppmax_u64<0xB1>(m);
        m = dppmax_u64<0x4E>(m);
        m = dppmax_u64<0x141>(m);
        m = dppmax_u64<0x140>(m);

        if (pk == m) {  // unique winner (disjoint index ranges)
          s_bxy = ((unsigned long long)__float_as_uint(gx) << 32) |
                  (unsigned long long)__float_as_uint(gy);
          __hip_atomic_store(&s_bz,
              ((unsigned long long)__float_as_uint(gz) << 32) | seq,
              __ATOMIC_RELEASE, __HIP_MEMORY_SCOPE_WORKGROUP);
          if (r == 0) {
            float* op = out + ((size_t)b * NSAMP + it) * 3;
            op[0] = gx; op[1] = gy; op[2] = gz;
          }
        }
      }
    }

    // --- all waves: spin on broadcast tag, then read winner coords ---
    unsigned long long bzv;
    do {
      bzv = __hip_atomic_load(&s_bz, __ATOMIC_ACQUIRE,
                              __HIP_MEMORY_SCOPE_WORKGROUP);
    } while ((bzv & 0xFFFFull) != seq);
    unsigned long long bxy = s_bxy;
    sx = __uint_as_float((unsigned)(bxy >> 32));
    sy = __uint_as_float((unsigned)bxy);
    sz = __uint_as_float((unsigned)(bzv >> 32));
  }
}

extern "C" void kernel_launch(void* const* d_in, const int* in_sizes, int n_in,
                              void* d_out, int out_size, void* d_ws,
                              size_t ws_size, hipStream_t stream) {
  const float* coords = (const float*)d_in[0];  // (16, 65536, 3) fp32
  // d_in[1] (features) is unused by the reference output.
  float* out = (float*)d_out;                   // (16, 2048, 3) fp32
  unsigned long long* slots = (unsigned long long*)d_ws;  // 2*16*16*4*8 = 16 KiB
  fps_kernel<<<dim3(BATCHES * PB), dim3(TPB), 0, stream>>>(coords, out, slots);
}